// Round 7
// baseline (174.117 us; speedup 1.0000x reference)
//
#include <hip/hip_runtime.h>
#include <cstdint>
#include <cstddef>

// ---------------------------------------------------------------------------
// RelativePositionMultiHeadAttention, B=4 L=1024 D=1024 H=16 dk=64
// Identity: BD[...,L-1:][b,h,i,j] = Q[b,h,i] . Er[4999-j]
//  => scores = Q @ (K + Er_flip)^T / 8  -> plain softmax attention.
// R13: gemm_qkv = m97-clone. Four hand-scheduled structures (R7/R8/R11/R12)
//     all tied at ~600 TF; the shared element was the per-phase
//     {s_barrier; lgkmcnt(0); sched_barrier(0)} pinning == the m141
//     anti-pattern (510 TF) that defeats the compiler's fine-grained
//     lgkmcnt(N) read/MFMA interleave (m97's actual mechanism, 874-912 TF).
//     New kernel: 128x128 tile, 4 waves (2x2 of 64x64), BK=64, 32 KB
//     single-buffer LDS, plain __syncthreads 2-barrier loop, NO inline asm,
//     conflict-free line-pair XOR swizzle (R12-verified both-sides),
//     768 blocks = 3/CU (m114 cross-block overlap), XCD-rect swizzle.
// attn / gemm_out / cast_all frozen as control (R10/R12).
// ---------------------------------------------------------------------------

typedef __attribute__((ext_vector_type(8))) short short8;   // 8 x bf16 (4 VGPR)
typedef __attribute__((ext_vector_type(4))) float f32x4;    // 4 x f32

#define MFMA_BF16(a, b, c) __builtin_amdgcn_mfma_f32_16x16x32_bf16((a), (b), (c), 0, 0, 0)

constexpr int kB = 4, kL = 1024, kD = 1024, kH = 16;
constexpr int kBL = kB * kL;   // 4096
constexpr float kScale = 0.125f * 1.44269504088896340736f;  // log2(e)/sqrt(dk)

static __device__ __forceinline__ unsigned short f32_to_bf16(float f) {
  union { float f; uint32_t u; } c; c.f = f;
  uint32_t u = c.u + 0x7fffu + ((c.u >> 16) & 1u);  // RNE
  return (unsigned short)(u >> 16);
}

static __device__ __forceinline__ uint32_t pack_bf16x2(float a, float b) {
  union { float f; uint32_t u; } ca, cb; ca.f = a; cb.f = b;
  return ((ca.u + 0x8000u) >> 16) | ((cb.u + 0x8000u) & 0xffff0000u);
}

static __device__ __forceinline__ void gload_lds16(const void* g, void* l) {
  __builtin_amdgcn_global_load_lds(
      (const __attribute__((address_space(1))) void*)g,
      (__attribute__((address_space(3))) void*)l, 16, 0, 0);
}

// ---------------- single fused cast: x, Wq, Wk, Wv, Wo -> bf16 ----------------
__global__ __launch_bounds__(256)
void cast_all(const float* __restrict__ x,  const float* __restrict__ Wq,
              const float* __restrict__ Wk, const float* __restrict__ Wv,
              const float* __restrict__ Wo,
              unsigned short* __restrict__ xb, unsigned short* __restrict__ Wcat,
              unsigned short* __restrict__ Wob) {
  int i = blockIdx.x * blockDim.x + threadIdx.x;
  const float* src;
  ushort4* dst;
  int off;
  if (i < 1048576) {
    src = x; dst = reinterpret_cast<ushort4*>(xb); off = i;
  } else {
    int j = i - 1048576;
    int seg = j >> 18;          // 0..3
    off = j & 262143;
    if (seg == 0)      { src = Wq; dst = reinterpret_cast<ushort4*>(Wcat); }
    else if (seg == 1) { src = Wk; dst = reinterpret_cast<ushort4*>(Wcat) + 262144; }
    else if (seg == 2) { src = Wv; dst = reinterpret_cast<ushort4*>(Wcat) + 524288; }
    else               { src = Wo; dst = reinterpret_cast<ushort4*>(Wob); }
  }
  float4 v = reinterpret_cast<const float4*>(src)[off];
  ushort4 o;
  o.x = f32_to_bf16(v.x); o.y = f32_to_bf16(v.y);
  o.z = f32_to_bf16(v.z); o.w = f32_to_bf16(v.w);
  dst[off] = o;
}

// ---------------- fused QKV GEMM  [4096 x 3072] = xb @ Wcat^T ----------------
// 128x128 tile, 4 waves (2M x 2N, wave tile 64x64), BK=64 in two K-halves.
// LDS 32 KiB single-buffer: A [kh][8 KiB] at 0, B [kh][8 KiB] at 16 KiB.
// Within an 8 KiB khalf block (128 rows x 32 elems): rows pack two-per-128B
// line, byte ^= ((line&3)<<4) swizzle -> ds_read_b128 frag reads 2-way free;
// inverse swizzle applied to per-lane GLOBAL source (rule 21; R12-verified).
// Plain 2-barrier loop: sync; stage 8x gload_lds16/thread; sync; compute.
// Compiler owns all waitcnt scheduling (no asm anywhere in the loop).
__global__ __launch_bounds__(256, 3)
void gemm_qkv(const unsigned short* __restrict__ A,   // 4096 x 1024 bf16
              const unsigned short* __restrict__ Bm,  // 3072 x 1024 bf16
              const float* __restrict__ bq, const float* __restrict__ bk,
              const float* __restrict__ bv,
              const float* __restrict__ Er,           // 5000x64 f32
              unsigned short* __restrict__ Qh, unsigned short* __restrict__ Kh,
              unsigned short* __restrict__ Vth) {
  __shared__ __align__(16) char smem[32768];
  const int tid  = threadIdx.x;
  const int lane = tid & 63, wave = tid >> 6;
  const int quad = lane >> 4, l15 = lane & 15, lhalf = l15 >> 1;
  const int wr = wave >> 1, wc = wave & 1;          // 2 x 2 wave grid

  // XCD swizzle: 768 blocks = 96/XCD; per-XCD rect 8M x 12N of 128-tiles.
  const int bid = blockIdx.x;
  const int xcd = bid & 7, idx = bid >> 3;          // idx 0..95
  const int mi = idx / 12, ni = idx - mi * 12;
  const int m0 = ((xcd >> 1) * 8 + mi) * 128;       // 32 M-tiles
  const int n0 = ((xcd & 1) * 12 + ni) * 128;       // 24 N-tiles

  // swizzled frag-read lane constant: frag row = wr*64 + mf*16 + l15
  // (resp. wc/nf); line = row>>1 -> line&3 == lhalf&3 (wr*32, mf*8 == 0 mod 4).
  const int lane_off = (l15 & 1) * 64 + ((quad * 16) ^ ((lhalf & 3) << 4));
  const int aoff = lhalf * 128 + lane_off + wr * 4096;  // + kh*8192 + mf*1024
  const int boff = lhalf * 128 + lane_off + wc * 4096;  // + kh*8192 + nf*1024

  // staging decoder (phys -> logical, involution; 512 x 16B units per khalf)
  int srow[2], scol[2];
#pragma unroll
  for (int j = 0; j < 2; ++j) {
    int poff = (j * 256 + tid) * 16;
    int L = poff ^ (((poff >> 7) & 3) << 4);
    srow[j] = ((L >> 7) << 1) | ((L >> 6) & 1);     // 0..127
    scol[j] = (L & 63) >> 1;                        // elem 0..31
  }

  auto stageA = [&](int kh, int tt) {               // 2 loads/thread
    char* dst = smem + kh * 8192 + tid * 16;
    const int kc = tt * 64 + kh * 32;
#pragma unroll
    for (int j = 0; j < 2; ++j)
      gload_lds16(A + (size_t)(m0 + srow[j]) * 1024 + kc + scol[j],
                  dst + j * 4096);
  };
  auto stageB = [&](int kh, int tt) {               // 2 loads/thread
    char* dst = smem + 16384 + kh * 8192 + tid * 16;
    const int kc = tt * 64 + kh * 32;
#pragma unroll
    for (int j = 0; j < 2; ++j)
      gload_lds16(Bm + (size_t)(n0 + srow[j]) * 1024 + kc + scol[j],
                  dst + j * 4096);
  };

  const f32x4 vzero = {0.f, 0.f, 0.f, 0.f};
  f32x4 acc[4][4];
#pragma unroll
  for (int i = 0; i < 4; ++i)
#pragma unroll
    for (int j = 0; j < 4; ++j) acc[i][j] = vzero;

  for (int t = 0; t < 16; ++t) {
    __syncthreads();                    // previous tile's reads done
    stageA(0, t); stageA(1, t); stageB(0, t); stageB(1, t);
    __syncthreads();                    // stage drained (vmcnt0 by semantics)
#pragma unroll
    for (int ks = 0; ks < 2; ++ks) {
      short8 af[4], bf[4];
#pragma unroll
      for (int mf = 0; mf < 4; ++mf)
        af[mf] = *(const short8*)(smem + ks * 8192 + aoff + mf * 1024);
#pragma unroll
      for (int nf = 0; nf < 4; ++nf)
        bf[nf] = *(const short8*)(smem + 16384 + ks * 8192 + boff + nf * 1024);
#pragma unroll
      for (int mf = 0; mf < 4; ++mf)
#pragma unroll
        for (int nf = 0; nf < 4; ++nf)
          acc[mf][nf] = MFMA_BF16(af[mf], bf[nf], acc[mf][nf]);
    }
  }
  __syncthreads();                      // before LDS arena reuse (V epilogue)

  // ---- epilogue: wave tile 64x64 at (m0+wr*64, n0+wc*64); single head ----
  const int gmb  = m0 + wr * 64;
  const int bb   = gmb >> 10, i0l = gmb & 1023;
  const int nb   = n0 + wc * 64;              // 64-aligned
  const int wsel = nb >> 10;                  // 0=Q 1=K 2=V (block-uniform)
  const int nin0 = nb & 1023;
  const int hh   = nin0 >> 6;
  const size_t bh = (size_t)(bb * 16 + hh);

  if (wsel == 0) {
#pragma unroll
    for (int nf = 0; nf < 4; ++nf) {
      const int nin = nin0 + nf * 16;
#pragma unroll
      for (int mf = 0; mf < 4; ++mf)
#pragma unroll
        for (int r = 0; r < 4; ++r) {
          const int i = i0l + mf * 16 + quad * 4 + r;
          float v = (acc[mf][nf][r] + bq[nin + l15]) * kScale;  // fold scale
          Qh[(bh * 1024 + i) * 64 + (nin & 63) + l15] = f32_to_bf16(v);
        }
    }
  } else if (wsel == 1) {
#pragma unroll
    for (int nf = 0; nf < 4; ++nf) {
      const int nin = nin0 + nf * 16;
      const int d0  = nin & 63;
#pragma unroll
      for (int mf = 0; mf < 4; ++mf)
#pragma unroll
        for (int r = 0; r < 4; ++r) {
          const int i = i0l + mf * 16 + quad * 4 + r;
          float v = acc[mf][nf][r] + bk[nin + l15] +
                    Er[(size_t)(4999 - i) * 64 + d0 + l15];
          Kh[(bh * 1024 + i) * 64 + d0 + l15] = f32_to_bf16(v);
        }
    }
  } else {
    // V: transpose 64(i) x 64(d) wave subtile through wave-private 8 KiB LDS.
    unsigned short* W = (unsigned short*)smem + (size_t)wave * 4096;  // [d][i]
#pragma unroll
    for (int nf = 0; nf < 4; ++nf) {
      const int nin = nin0 + nf * 16;
#pragma unroll
      for (int mf = 0; mf < 4; ++mf) {
        ushort4 pk;
        pk.x = f32_to_bf16(acc[mf][nf][0] + bv[nin + l15]);
        pk.y = f32_to_bf16(acc[mf][nf][1] + bv[nin + l15]);
        pk.z = f32_to_bf16(acc[mf][nf][2] + bv[nin + l15]);
        pk.w = f32_to_bf16(acc[mf][nf][3] + bv[nin + l15]);
        // W[d][i]: d = nf*16+l15 (0..63), i = mf*16+quad*4+(0..3)
        *(ushort4*)&W[(size_t)(nf * 16 + l15) * 64 + mf * 16 + quad * 4] = pk;
      }
    }
    // wave-private region: compiler inserts lgkm waits before re-read
#pragma unroll
    for (int p = 0; p < 8; ++p) {
      const int u = p * 64 + lane;              // 512 x 16B units
      const int d = u >> 3, ch = (u & 7) * 8;
      short8 vv = *(const short8*)&W[(size_t)d * 64 + ch];
      *(short8*)&Vth[(bh * 64 + d) * 1024 + i0l + ch] = vv;
    }
  }
}

// ---------------- out GEMM  out[4096,1024] = Aoh @ Wo^T + b_o ----------------
// (unchanged from R10 -- control)
__global__ __launch_bounds__(256)
void gemm_out(const unsigned short* __restrict__ A,   // 4096 x 1024
              const unsigned short* __restrict__ Bm,  // 1024 x 1024
              const float* __restrict__ bias,
              float* __restrict__ outf) {
  __shared__ __align__(16) char smem[49152];   // [buf: A 16KB | B 8KB] x2
  const int tid  = threadIdx.x;
  const int lane = tid & 63, wave = tid >> 6;
  const int quad = lane >> 4, l15 = lane & 15;
  const int m0 = blockIdx.y * 128, n0 = blockIdx.x * 64;

  const int afo = (l15 >> 1) * 128 + (l15 & 1) * 64 +
                  ((quad * 16) ^ (((l15 >> 1) & 3) << 4));

  int arow[4], acol[4], akh[4];
#pragma unroll
  for (int j = 0; j < 4; ++j) {
    int u = j * 256 + tid;                 // 0..1023 (A: 1024 x 16B units)
    akh[j] = u >> 9;
    int poff = (u & 511) * 16;
    int L = poff ^ (((poff >> 7) & 3) << 4);
    arow[j] = ((L >> 7) << 1) | ((L >> 6) & 1);     // 0..127
    acol[j] = (L & 63) >> 1;                        // elem 0..31
  }
  int brow[2], bcol[2], bkh[2];
#pragma unroll
  for (int j = 0; j < 2; ++j) {
    int u = j * 256 + tid;                 // 0..511 (B: 512 x 16B units)
    bkh[j] = u >> 8;
    int poff = (u & 255) * 16;
    int L = poff ^ (((poff >> 7) & 3) << 4);
    brow[j] = ((L >> 7) << 1) | ((L >> 6) & 1);     // 0..63
    bcol[j] = (L & 63) >> 1;
  }

  auto stageG = [&](int buf, int t) {      // 6 loads/thread
    char* base = smem + buf * 24576;
    const int kc = t * 64;
#pragma unroll
    for (int j = 0; j < 4; ++j) {
      int u = j * 256 + tid;
      gload_lds16(A + (size_t)(m0 + arow[j]) * 1024 + kc + akh[j] * 32 + acol[j],
                  base + u * 16);
    }
#pragma unroll
    for (int j = 0; j < 2; ++j) {
      int u = j * 256 + tid;
      gload_lds16(Bm + (size_t)(n0 + brow[j]) * 1024 + kc + bkh[j] * 32 + bcol[j],
                  base + 16384 + u * 16);
    }
  };

  const f32x4 vzero = {0.f, 0.f, 0.f, 0.f};
  f32x4 acc[2][4];
#pragma unroll
  for (int i = 0; i < 2; ++i)
#pragma unroll
    for (int j = 0; j < 4; ++j) acc[i][j] = vzero;

  stageG(0, 0);
  for (int t = 0; t < 16; ++t) {
    const int cur = t & 1;
    if (t < 15) stageG(cur ^ 1, t + 1);
    if (t < 15) asm volatile("s_waitcnt vmcnt(6)" ::: "memory");
    else        asm volatile("s_waitcnt vmcnt(0)" ::: "memory");
    __builtin_amdgcn_s_barrier();
    __builtin_amdgcn_sched_barrier(0);
    const char* Ab = smem + cur * 24576;
    const char* Bb = Ab + 16384;
#pragma unroll
    for (int ks = 0; ks < 2; ++ks) {
      short8 af[2], bfv[4];
#pragma unroll
      for (int mt = 0; mt < 2; ++mt)
        af[mt] = *(const short8*)(Ab + ks * 8192 + wave * 2048 + mt * 1024 + afo);
#pragma unroll
      for (int nt = 0; nt < 4; ++nt)
        bfv[nt] = *(const short8*)(Bb + ks * 4096 + nt * 1024 + afo);
#pragma unroll
      for (int mt = 0; mt < 2; ++mt)
#pragma unroll
        for (int nt = 0; nt < 4; ++nt)
          acc[mt][nt] = MFMA_BF16(af[mt], bfv[nt], acc[mt][nt]);
    }
    __builtin_amdgcn_s_barrier();
    __builtin_amdgcn_sched_barrier(0);
  }

#pragma unroll
  for (int mt = 0; mt < 2; ++mt)
#pragma unroll
    for (int nt = 0; nt < 4; ++nt)
#pragma unroll
      for (int r = 0; r < 4; ++r) {
        const int gm = m0 + wave * 32 + mt * 16 + quad * 4 + r;
        const int gn = n0 + nt * 16 + l15;
        outf[(size_t)gm * 1024 + gn] = acc[mt][nt][r] + bias[gn];
      }
}

// ---------------- flash attention, LDS-staged K/V, prefetch ----------------
// (unchanged from R10 -- control)
__global__ __launch_bounds__(256)
void attn_kernel(const unsigned short* __restrict__ Q,
                 const unsigned short* __restrict__ Kp,
                 const unsigned short* __restrict__ Vt,
                 unsigned short* __restrict__ Ao) {
  __shared__ unsigned short Ks[2][2][64 * 32];  // [buf][half][key][32]
  __shared__ unsigned short Vs[2][2][64 * 32];  // [buf][half][d][32]
  __shared__ unsigned short Plds[4][32 * 72];   // per-wave P rows
  const int tid  = threadIdx.x;
  const int lane = tid & 63, wave = tid >> 6;
  const int quad = lane >> 4, l15 = lane & 15;
  const int bh = blockIdx.x;
  const int qb = blockIdx.y;
  const size_t base  = (size_t)bh * (kL * 64);
  const size_t vbase = (size_t)bh * (64 * kL);
  const int i0 = qb * 128 + wave * 32;

  short8 qf[2][2];
#pragma unroll
  for (int mt = 0; mt < 2; ++mt)
#pragma unroll
    for (int ks = 0; ks < 2; ++ks)
      qf[mt][ks] = *(const short8*)
          &Q[base + (size_t)(i0 + mt * 16 + l15) * 64 + ks * 32 + quad * 8];

  auto stage = [&](int buf, int kb) {
#pragma unroll
    for (int j = 0; j < 2; ++j) {
      int u = j * 256 + tid;
      int half = u >> 8, row = (u >> 2) & 63, c = (u & 3) * 8;
      gload_lds16(Kp + base + (size_t)(kb * 64 + row) * 64 + half * 32 + c,
                  (char*)&Ks[buf][0][0] + (size_t)u * 16);
      gload_lds16(Vt + vbase + (size_t)row * kL + kb * 64 + half * 32 + c,
                  (char*)&Vs[buf][0][0] + (size_t)u * 16);
    }
  };

  const f32x4 vzero = {0.f, 0.f, 0.f, 0.f};
  f32x4 of[2][4];
#pragma unroll
  for (int mt = 0; mt < 2; ++mt)
#pragma unroll
    for (int dt = 0; dt < 4; ++dt) of[mt][dt] = vzero;
  float lsum[2] = {0.f, 0.f};

  unsigned short* Pw = Plds[wave];

  stage(0, 0);
  __syncthreads();

  for (int kb = 0; kb < 16; ++kb) {
    const int cur = kb & 1, nxt = cur ^ 1;
    if (kb < 15) stage(nxt, kb + 1);

    short8 kf[4][2];
#pragma unroll
    for (int nt = 0; nt < 4; ++nt)
#pragma unroll
      for (int ks = 0; ks < 2; ++ks)
        kf[nt][ks] = *(const short8*)&Ks[cur][ks][(nt * 16 + l15) * 32 + quad * 8];
    // S^T = K . Q^T : lane holds P[i = mt*16+l15][key = nt*16 + quad*4 + r]
    f32x4 sf[2][4];
#pragma unroll
    for (int mt = 0; mt < 2; ++mt)
#pragma unroll
      for (int nt = 0; nt < 4; ++nt) {
        sf[mt][nt] = MFMA_BF16(kf[nt][0], qf[mt][0], vzero);
        sf[mt][nt] = MFMA_BF16(kf[nt][1], qf[mt][1], sf[mt][nt]);
      }

#pragma unroll
    for (int mt = 0; mt < 2; ++mt)
#pragma unroll
      for (int nt = 0; nt < 4; ++nt) {
        float p0 = __builtin_amdgcn_exp2f(sf[mt][nt][0]);
        float p1 = __builtin_amdgcn_exp2f(sf[mt][nt][1]);
        float p2 = __builtin_amdgcn_exp2f(sf[mt][nt][2]);
        float p3 = __builtin_amdgcn_exp2f(sf[mt][nt][3]);
        lsum[mt] += (p0 + p1) + (p2 + p3);
        uint2 w;
        w.x = pack_bf16x2(p0, p1);
        w.y = pack_bf16x2(p2, p3);
        *(uint2*)&Pw[(mt * 16 + l15) * 72 + nt * 16 + quad * 4] = w;
      }
    short8 pf[2][2];
#pragma unroll
    for (int mt = 0; mt < 2; ++mt)
#pragma unroll
      for (int ks = 0; ks < 2; ++ks)
        pf[mt][ks] = *(const short8*)&Pw[(mt * 16 + l15) * 72 + ks * 32 + quad * 8];

    short8 vf[4][2];
#pragma unroll
    for (int dt = 0; dt < 4; ++dt)
#pragma unroll
      for (int ks = 0; ks < 2; ++ks)
        vf[dt][ks] = *(const short8*)&Vs[cur][ks][(dt * 16 + l15) * 32 + quad * 8];
#pragma unroll
    for (int mt = 0; mt < 2; ++mt)
#pragma unroll
      for (int dt = 0; dt < 4; ++dt) {
        of[mt][dt] = MFMA_BF16(pf[mt][0], vf[dt][0], of[mt][dt]);
        of[mt][dt] = MFMA_BF16(pf[mt][1], vf[dt][1], of[mt][dt]);
      }

    __syncthreads();
  }

  // row-sum finalize: lane l15 holds full sum for row i = mt*16+l15 after
  // cross-quad reduce; broadcast to (quad,r) consumers.
  float rl[2][4];
#pragma unroll
  for (int mt = 0; mt < 2; ++mt) {
    float s = lsum[mt];
    s += __shfl_xor(s, 16);
    s += __shfl_xor(s, 32);
#pragma unroll
    for (int r = 0; r < 4; ++r)
      rl[mt][r] = __builtin_amdgcn_rcpf(__shfl(s, quad * 4 + r));
  }

  const int b = bh >> 4, h = bh & 15;
#pragma unroll
  for (int mt = 0; mt < 2; ++mt)
#pragma unroll
    for (int dt = 0; dt < 4; ++dt)
#pragma unroll
      for (int r = 0; r < 4; ++r) {
        const int ig = i0 + mt * 16 + quad * 4 + r;
        float v = of[mt][dt][r] * rl[mt][r];
        Ao[((size_t)(b * 1024 + ig)) * 1024 + h * 64 + dt * 16 + l15] = f32_to_bf16(v);
      }
}

// ---------------------------------------------------------------------------
extern "C" void kernel_launch(void* const* d_in, const int* in_sizes, int n_in,
                              void* d_out, int out_size, void* d_ws, size_t ws_size,
                              hipStream_t stream) {
  const float* x   = (const float*)d_in[0];
  const float* W_q = (const float*)d_in[1];
  const float* b_q = (const float*)d_in[2];
  const float* W_k = (const float*)d_in[3];
  const float* b_k = (const float*)d_in[4];
  const float* W_v = (const float*)d_in[5];
  const float* b_v = (const float*)d_in[6];
  const float* W_o = (const float*)d_in[7];
  const float* b_o = (const float*)d_in[8];
  const float* Er  = (const float*)d_in[9];
  float* out = (float*)d_out;

  char* ws = (char*)d_ws;
  unsigned short* xb   = (unsigned short*)(ws + (size_t)0);          // 8 MB
  unsigned short* Wcat = (unsigned short*)(ws + ((size_t)8  << 20)); // 6 MB (Wq|Wk|Wv)
  unsigned short* Wob  = (unsigned short*)(ws + ((size_t)14 << 20)); // 2 MB
  unsigned short* Qh   = (unsigned short*)(ws + ((size_t)16 << 20)); // 8 MB [bh][i][d]
  unsigned short* Kh   = (unsigned short*)(ws + ((size_t)24 << 20)); // 8 MB [bh][i][d]
  unsigned short* Vth  = (unsigned short*)(ws + ((size_t)32 << 20)); // 8 MB [bh][d][i]
  unsigned short* Aoh  = (unsigned short*)(ws + ((size_t)40 << 20)); // 8 MB [b*L][D]

  cast_all<<<8192, 256, 0, stream>>>(x, W_q, W_k, W_v, W_o, xb, Wcat, Wob);

  gemm_qkv<<<768, 256, 0, stream>>>(
      xb, Wcat, b_q, b_k, b_v, Er, Qh, Kh, Vth);

  attn_kernel<<<dim3(kB * kH, kL / 128), 256, 0, stream>>>(Qh, Kh, Vth, Aoh);

  gemm_out<<<dim3(16, 32), 256, 0, stream>>>(Aoh, Wob, b_o, out);
}

// Round 8
// 170.899 us; speedup vs baseline: 1.0188x; 1.0188x over previous
//
#include <hip/hip_runtime.h>
#include <cstdint>
#include <cstddef>

// ---------------------------------------------------------------------------
// RelativePositionMultiHeadAttention, B=4 L=1024 D=1024 H=16 dk=64
// Identity: BD[...,L-1:][b,h,i,j] = Q[b,h,i] . Er[4999-j]
//  => scores = Q @ (K + Er_flip)^T / 8  -> plain softmax attention.
// R14: attn K/V LDS tiles moved to the line-pair XOR-swizzled layout
//     (2 rows per 128B line, byte ^= (line&3)<<4; inverse swizzle on global
//     source) -- the old [key][64B-row] layout made every kf/vf ds_read_b128
//     an 8-way bank conflict (bank = (l15&1)*16 + quad*4: 16 lanes -> 2
//     banks). 16-20 conflicted reads/iter/wave was attn's dominant LDS cost.
//     Same formulas as the R12/R13-verified GEMM staging (khalf = 4 KB).
// gemm_qkv (R13 m97-clone), gemm_out (R10), cast_all frozen as control.
// ---------------------------------------------------------------------------

typedef __attribute__((ext_vector_type(8))) short short8;   // 8 x bf16 (4 VGPR)
typedef __attribute__((ext_vector_type(4))) float f32x4;    // 4 x f32

#define MFMA_BF16(a, b, c) __builtin_amdgcn_mfma_f32_16x16x32_bf16((a), (b), (c), 0, 0, 0)

constexpr int kB = 4, kL = 1024, kD = 1024, kH = 16;
constexpr int kBL = kB * kL;   // 4096
constexpr float kScale = 0.125f * 1.44269504088896340736f;  // log2(e)/sqrt(dk)

static __device__ __forceinline__ unsigned short f32_to_bf16(float f) {
  union { float f; uint32_t u; } c; c.f = f;
  uint32_t u = c.u + 0x7fffu + ((c.u >> 16) & 1u);  // RNE
  return (unsigned short)(u >> 16);
}

static __device__ __forceinline__ uint32_t pack_bf16x2(float a, float b) {
  union { float f; uint32_t u; } ca, cb; ca.f = a; cb.f = b;
  return ((ca.u + 0x8000u) >> 16) | ((cb.u + 0x8000u) & 0xffff0000u);
}

static __device__ __forceinline__ void gload_lds16(const void* g, void* l) {
  __builtin_amdgcn_global_load_lds(
      (const __attribute__((address_space(1))) void*)g,
      (__attribute__((address_space(3))) void*)l, 16, 0, 0);
}

// ---------------- single fused cast: x, Wq, Wk, Wv, Wo -> bf16 ----------------
__global__ __launch_bounds__(256)
void cast_all(const float* __restrict__ x,  const float* __restrict__ Wq,
              const float* __restrict__ Wk, const float* __restrict__ Wv,
              const float* __restrict__ Wo,
              unsigned short* __restrict__ xb, unsigned short* __restrict__ Wcat,
              unsigned short* __restrict__ Wob) {
  int i = blockIdx.x * blockDim.x + threadIdx.x;
  const float* src;
  ushort4* dst;
  int off;
  if (i < 1048576) {
    src = x; dst = reinterpret_cast<ushort4*>(xb); off = i;
  } else {
    int j = i - 1048576;
    int seg = j >> 18;          // 0..3
    off = j & 262143;
    if (seg == 0)      { src = Wq; dst = reinterpret_cast<ushort4*>(Wcat); }
    else if (seg == 1) { src = Wk; dst = reinterpret_cast<ushort4*>(Wcat) + 262144; }
    else if (seg == 2) { src = Wv; dst = reinterpret_cast<ushort4*>(Wcat) + 524288; }
    else               { src = Wo; dst = reinterpret_cast<ushort4*>(Wob); }
  }
  float4 v = reinterpret_cast<const float4*>(src)[off];
  ushort4 o;
  o.x = f32_to_bf16(v.x); o.y = f32_to_bf16(v.y);
  o.z = f32_to_bf16(v.z); o.w = f32_to_bf16(v.w);
  dst[off] = o;
}

// ---------------- fused QKV GEMM  [4096 x 3072] = xb @ Wcat^T ----------------
// (unchanged from R13 -- control) 128x128 tile, 4 waves, 32 KB single-buffer,
// plain 2-barrier loop, line-pair XOR swizzle both sides, 768 blocks (3/CU).
__global__ __launch_bounds__(256, 3)
void gemm_qkv(const unsigned short* __restrict__ A,   // 4096 x 1024 bf16
              const unsigned short* __restrict__ Bm,  // 3072 x 1024 bf16
              const float* __restrict__ bq, const float* __restrict__ bk,
              const float* __restrict__ bv,
              const float* __restrict__ Er,           // 5000x64 f32
              unsigned short* __restrict__ Qh, unsigned short* __restrict__ Kh,
              unsigned short* __restrict__ Vth) {
  __shared__ __align__(16) char smem[32768];
  const int tid  = threadIdx.x;
  const int lane = tid & 63, wave = tid >> 6;
  const int quad = lane >> 4, l15 = lane & 15, lhalf = l15 >> 1;
  const int wr = wave >> 1, wc = wave & 1;          // 2 x 2 wave grid

  const int bid = blockIdx.x;
  const int xcd = bid & 7, idx = bid >> 3;          // idx 0..95
  const int mi = idx / 12, ni = idx - mi * 12;
  const int m0 = ((xcd >> 1) * 8 + mi) * 128;       // 32 M-tiles
  const int n0 = ((xcd & 1) * 12 + ni) * 128;       // 24 N-tiles

  const int lane_off = (l15 & 1) * 64 + ((quad * 16) ^ ((lhalf & 3) << 4));
  const int aoff = lhalf * 128 + lane_off + wr * 4096;  // + kh*8192 + mf*1024
  const int boff = lhalf * 128 + lane_off + wc * 4096;  // + kh*8192 + nf*1024

  int srow[2], scol[2];
#pragma unroll
  for (int j = 0; j < 2; ++j) {
    int poff = (j * 256 + tid) * 16;
    int L = poff ^ (((poff >> 7) & 3) << 4);
    srow[j] = ((L >> 7) << 1) | ((L >> 6) & 1);     // 0..127
    scol[j] = (L & 63) >> 1;                        // elem 0..31
  }

  auto stageA = [&](int kh, int tt) {               // 2 loads/thread
    char* dst = smem + kh * 8192 + tid * 16;
    const int kc = tt * 64 + kh * 32;
#pragma unroll
    for (int j = 0; j < 2; ++j)
      gload_lds16(A + (size_t)(m0 + srow[j]) * 1024 + kc + scol[j],
                  dst + j * 4096);
  };
  auto stageB = [&](int kh, int tt) {               // 2 loads/thread
    char* dst = smem + 16384 + kh * 8192 + tid * 16;
    const int kc = tt * 64 + kh * 32;
#pragma unroll
    for (int j = 0; j < 2; ++j)
      gload_lds16(Bm + (size_t)(n0 + srow[j]) * 1024 + kc + scol[j],
                  dst + j * 4096);
  };

  const f32x4 vzero = {0.f, 0.f, 0.f, 0.f};
  f32x4 acc[4][4];
#pragma unroll
  for (int i = 0; i < 4; ++i)
#pragma unroll
    for (int j = 0; j < 4; ++j) acc[i][j] = vzero;

  for (int t = 0; t < 16; ++t) {
    __syncthreads();                    // previous tile's reads done
    stageA(0, t); stageA(1, t); stageB(0, t); stageB(1, t);
    __syncthreads();                    // stage drained (vmcnt0 by semantics)
#pragma unroll
    for (int ks = 0; ks < 2; ++ks) {
      short8 af[4], bf[4];
#pragma unroll
      for (int mf = 0; mf < 4; ++mf)
        af[mf] = *(const short8*)(smem + ks * 8192 + aoff + mf * 1024);
#pragma unroll
      for (int nf = 0; nf < 4; ++nf)
        bf[nf] = *(const short8*)(smem + 16384 + ks * 8192 + boff + nf * 1024);
#pragma unroll
      for (int mf = 0; mf < 4; ++mf)
#pragma unroll
        for (int nf = 0; nf < 4; ++nf)
          acc[mf][nf] = MFMA_BF16(af[mf], bf[nf], acc[mf][nf]);
    }
  }
  __syncthreads();                      // before LDS arena reuse (V epilogue)

  // ---- epilogue: wave tile 64x64 at (m0+wr*64, n0+wc*64); single head ----
  const int gmb  = m0 + wr * 64;
  const int bb   = gmb >> 10, i0l = gmb & 1023;
  const int nb   = n0 + wc * 64;              // 64-aligned
  const int wsel = nb >> 10;                  // 0=Q 1=K 2=V (block-uniform)
  const int nin0 = nb & 1023;
  const int hh   = nin0 >> 6;
  const size_t bh = (size_t)(bb * 16 + hh);

  if (wsel == 0) {
#pragma unroll
    for (int nf = 0; nf < 4; ++nf) {
      const int nin = nin0 + nf * 16;
#pragma unroll
      for (int mf = 0; mf < 4; ++mf)
#pragma unroll
        for (int r = 0; r < 4; ++r) {
          const int i = i0l + mf * 16 + quad * 4 + r;
          float v = (acc[mf][nf][r] + bq[nin + l15]) * kScale;  // fold scale
          Qh[(bh * 1024 + i) * 64 + (nin & 63) + l15] = f32_to_bf16(v);
        }
    }
  } else if (wsel == 1) {
#pragma unroll
    for (int nf = 0; nf < 4; ++nf) {
      const int nin = nin0 + nf * 16;
      const int d0  = nin & 63;
#pragma unroll
      for (int mf = 0; mf < 4; ++mf)
#pragma unroll
        for (int r = 0; r < 4; ++r) {
          const int i = i0l + mf * 16 + quad * 4 + r;
          float v = acc[mf][nf][r] + bk[nin + l15] +
                    Er[(size_t)(4999 - i) * 64 + d0 + l15];
          Kh[(bh * 1024 + i) * 64 + d0 + l15] = f32_to_bf16(v);
        }
    }
  } else {
    // V: transpose 64(i) x 64(d) wave subtile through wave-private 8 KiB LDS.
    unsigned short* W = (unsigned short*)smem + (size_t)wave * 4096;  // [d][i]
#pragma unroll
    for (int nf = 0; nf < 4; ++nf) {
      const int nin = nin0 + nf * 16;
#pragma unroll
      for (int mf = 0; mf < 4; ++mf) {
        ushort4 pk;
        pk.x = f32_to_bf16(acc[mf][nf][0] + bv[nin + l15]);
        pk.y = f32_to_bf16(acc[mf][nf][1] + bv[nin + l15]);
        pk.z = f32_to_bf16(acc[mf][nf][2] + bv[nin + l15]);
        pk.w = f32_to_bf16(acc[mf][nf][3] + bv[nin + l15]);
        // W[d][i]: d = nf*16+l15 (0..63), i = mf*16+quad*4+(0..3)
        *(ushort4*)&W[(size_t)(nf * 16 + l15) * 64 + mf * 16 + quad * 4] = pk;
      }
    }
    // wave-private region: compiler inserts lgkm waits before re-read
#pragma unroll
    for (int p = 0; p < 8; ++p) {
      const int u = p * 64 + lane;              // 512 x 16B units
      const int d = u >> 3, ch = (u & 7) * 8;
      short8 vv = *(const short8*)&W[(size_t)d * 64 + ch];
      *(short8*)&Vth[(bh * 64 + d) * 1024 + i0l + ch] = vv;
    }
  }
}

// ---------------- out GEMM  out[4096,1024] = Aoh @ Wo^T + b_o ----------------
// (unchanged from R10 -- control)
__global__ __launch_bounds__(256)
void gemm_out(const unsigned short* __restrict__ A,   // 4096 x 1024
              const unsigned short* __restrict__ Bm,  // 1024 x 1024
              const float* __restrict__ bias,
              float* __restrict__ outf) {
  __shared__ __align__(16) char smem[49152];   // [buf: A 16KB | B 8KB] x2
  const int tid  = threadIdx.x;
  const int lane = tid & 63, wave = tid >> 6;
  const int quad = lane >> 4, l15 = lane & 15;
  const int m0 = blockIdx.y * 128, n0 = blockIdx.x * 64;

  const int afo = (l15 >> 1) * 128 + (l15 & 1) * 64 +
                  ((quad * 16) ^ (((l15 >> 1) & 3) << 4));

  int arow[4], acol[4], akh[4];
#pragma unroll
  for (int j = 0; j < 4; ++j) {
    int u = j * 256 + tid;                 // 0..1023 (A: 1024 x 16B units)
    akh[j] = u >> 9;
    int poff = (u & 511) * 16;
    int L = poff ^ (((poff >> 7) & 3) << 4);
    arow[j] = ((L >> 7) << 1) | ((L >> 6) & 1);     // 0..127
    acol[j] = (L & 63) >> 1;                        // elem 0..31
  }
  int brow[2], bcol[2], bkh[2];
#pragma unroll
  for (int j = 0; j < 2; ++j) {
    int u = j * 256 + tid;                 // 0..511 (B: 512 x 16B units)
    bkh[j] = u >> 8;
    int poff = (u & 255) * 16;
    int L = poff ^ (((poff >> 7) & 3) << 4);
    brow[j] = ((L >> 7) << 1) | ((L >> 6) & 1);     // 0..63
    bcol[j] = (L & 63) >> 1;
  }

  auto stageG = [&](int buf, int t) {      // 6 loads/thread
    char* base = smem + buf * 24576;
    const int kc = t * 64;
#pragma unroll
    for (int j = 0; j < 4; ++j) {
      int u = j * 256 + tid;
      gload_lds16(A + (size_t)(m0 + arow[j]) * 1024 + kc + akh[j] * 32 + acol[j],
                  base + u * 16);
    }
#pragma unroll
    for (int j = 0; j < 2; ++j) {
      int u = j * 256 + tid;
      gload_lds16(Bm + (size_t)(n0 + brow[j]) * 1024 + kc + bkh[j] * 32 + bcol[j],
                  base + 16384 + u * 16);
    }
  };

  const f32x4 vzero = {0.f, 0.f, 0.f, 0.f};
  f32x4 acc[2][4];
#pragma unroll
  for (int i = 0; i < 2; ++i)
#pragma unroll
    for (int j = 0; j < 4; ++j) acc[i][j] = vzero;

  stageG(0, 0);
  for (int t = 0; t < 16; ++t) {
    const int cur = t & 1;
    if (t < 15) stageG(cur ^ 1, t + 1);
    if (t < 15) asm volatile("s_waitcnt vmcnt(6)" ::: "memory");
    else        asm volatile("s_waitcnt vmcnt(0)" ::: "memory");
    __builtin_amdgcn_s_barrier();
    __builtin_amdgcn_sched_barrier(0);
    const char* Ab = smem + cur * 24576;
    const char* Bb = Ab + 16384;
#pragma unroll
    for (int ks = 0; ks < 2; ++ks) {
      short8 af[2], bfv[4];
#pragma unroll
      for (int mt = 0; mt < 2; ++mt)
        af[mt] = *(const short8*)(Ab + ks * 8192 + wave * 2048 + mt * 1024 + afo);
#pragma unroll
      for (int nt = 0; nt < 4; ++nt)
        bfv[nt] = *(const short8*)(Bb + ks * 4096 + nt * 1024 + afo);
#pragma unroll
      for (int mt = 0; mt < 2; ++mt)
#pragma unroll
        for (int nt = 0; nt < 4; ++nt)
          acc[mt][nt] = MFMA_BF16(af[mt], bfv[nt], acc[mt][nt]);
    }
    __builtin_amdgcn_s_barrier();
    __builtin_amdgcn_sched_barrier(0);
  }

#pragma unroll
  for (int mt = 0; mt < 2; ++mt)
#pragma unroll
    for (int nt = 0; nt < 4; ++nt)
#pragma unroll
      for (int r = 0; r < 4; ++r) {
        const int gm = m0 + wave * 32 + mt * 16 + quad * 4 + r;
        const int gn = n0 + nt * 16 + l15;
        outf[(size_t)gm * 1024 + gn] = acc[mt][nt][r] + bias[gn];
      }
}

// ---------------- flash attention, LDS-staged K/V, prefetch ----------------
// grid (64 bh, 8 qblocks of 128), 256 threads. Wave owns 32 query rows.
// Q pre-scaled by log2(e)/8; no-max softmax (exp2 cannot overflow here).
// Swapped QK^T: sf = mfma(K,Q) -> lane holds P[i=mt*16+l15][key=16nt+4q+r].
// R14: K/V LDS in line-pair XOR-swizzled layout (khalf = 4 KB blocks):
//   logical L = (row>>1)*128 + (row&1)*64 + elem*2; phys = L ^ ((L>>7&3)<<4).
//   Frag reads (row = {nt|dt}*16 + l15) are conflict-free (was 8-way).
__global__ __launch_bounds__(256)
void attn_kernel(const unsigned short* __restrict__ Q,
                 const unsigned short* __restrict__ Kp,
                 const unsigned short* __restrict__ Vt,
                 unsigned short* __restrict__ Ao) {
  __shared__ __align__(16) char KV[32768];      // K [buf][kh][4K] | V at +16K
  __shared__ unsigned short Plds[4][32 * 72];   // per-wave P rows
  const int tid  = threadIdx.x;
  const int lane = tid & 63, wave = tid >> 6;
  const int quad = lane >> 4, l15 = lane & 15, lhalf = l15 >> 1;
  const int bh = blockIdx.x;
  const int qb = blockIdx.y;
  const size_t base  = (size_t)bh * (kL * 64);
  const size_t vbase = (size_t)bh * (64 * kL);
  const int i0 = qb * 128 + wave * 32;

  short8 qf[2][2];
#pragma unroll
  for (int mt = 0; mt < 2; ++mt)
#pragma unroll
    for (int ks = 0; ks < 2; ++ks)
      qf[mt][ks] = *(const short8*)
          &Q[base + (size_t)(i0 + mt * 16 + l15) * 64 + ks * 32 + quad * 8];

  // staging decoder (phys tid*16 -> logical row/col; involution)
  int srow, scol;
  {
    int poff = tid * 16;
    int L = poff ^ (((poff >> 7) & 3) << 4);
    srow = ((L >> 7) << 1) | ((L >> 6) & 1);    // 0..63
    scol = (L & 63) >> 1;                       // elem 0..31
  }

  auto stage = [&](int buf, int kb) {           // 4 loads/thread
#pragma unroll
    for (int kh = 0; kh < 2; ++kh) {
      gload_lds16(Kp + base + (size_t)(kb * 64 + srow) * 64 + kh * 32 + scol,
                  KV + buf * 8192 + kh * 4096 + tid * 16);
      gload_lds16(Vt + vbase + (size_t)srow * kL + kb * 64 + kh * 32 + scol,
                  KV + 16384 + buf * 8192 + kh * 4096 + tid * 16);
    }
  };

  // swizzled frag-read lane constant (row = frag*16 + l15):
  const int lane_off = lhalf * 128 + (l15 & 1) * 64 +
                       ((quad * 16) ^ ((lhalf & 3) << 4));

  const f32x4 vzero = {0.f, 0.f, 0.f, 0.f};
  f32x4 of[2][4];
#pragma unroll
  for (int mt = 0; mt < 2; ++mt)
#pragma unroll
    for (int dt = 0; dt < 4; ++dt) of[mt][dt] = vzero;
  float lsum[2] = {0.f, 0.f};

  unsigned short* Pw = Plds[wave];

  stage(0, 0);
  __syncthreads();

  for (int kb = 0; kb < 16; ++kb) {
    const int cur = kb & 1, nxt = cur ^ 1;
    if (kb < 15) stage(nxt, kb + 1);

    short8 kf[4][2];
#pragma unroll
    for (int nt = 0; nt < 4; ++nt)
#pragma unroll
      for (int ks = 0; ks < 2; ++ks)
        kf[nt][ks] = *(const short8*)
            (KV + cur * 8192 + ks * 4096 + lane_off + nt * 1024);
    // S^T = K . Q^T : lane holds P[i = mt*16+l15][key = nt*16 + quad*4 + r]
    f32x4 sf[2][4];
#pragma unroll
    for (int mt = 0; mt < 2; ++mt)
#pragma unroll
      for (int nt = 0; nt < 4; ++nt) {
        sf[mt][nt] = MFMA_BF16(kf[nt][0], qf[mt][0], vzero);
        sf[mt][nt] = MFMA_BF16(kf[nt][1], qf[mt][1], sf[mt][nt]);
      }

#pragma unroll
    for (int mt = 0; mt < 2; ++mt)
#pragma unroll
      for (int nt = 0; nt < 4; ++nt) {
        float p0 = __builtin_amdgcn_exp2f(sf[mt][nt][0]);
        float p1 = __builtin_amdgcn_exp2f(sf[mt][nt][1]);
        float p2 = __builtin_amdgcn_exp2f(sf[mt][nt][2]);
        float p3 = __builtin_amdgcn_exp2f(sf[mt][nt][3]);
        lsum[mt] += (p0 + p1) + (p2 + p3);
        uint2 w;
        w.x = pack_bf16x2(p0, p1);
        w.y = pack_bf16x2(p2, p3);
        *(uint2*)&Pw[(mt * 16 + l15) * 72 + nt * 16 + quad * 4] = w;
      }
    short8 pf[2][2];
#pragma unroll
    for (int mt = 0; mt < 2; ++mt)
#pragma unroll
      for (int ks = 0; ks < 2; ++ks)
        pf[mt][ks] = *(const short8*)&Pw[(mt * 16 + l15) * 72 + ks * 32 + quad * 8];

    short8 vf[4][2];
#pragma unroll
    for (int dt = 0; dt < 4; ++dt)
#pragma unroll
      for (int ks = 0; ks < 2; ++ks)
        vf[dt][ks] = *(const short8*)
            (KV + 16384 + cur * 8192 + ks * 4096 + lane_off + dt * 1024);
#pragma unroll
    for (int mt = 0; mt < 2; ++mt)
#pragma unroll
      for (int dt = 0; dt < 4; ++dt) {
        of[mt][dt] = MFMA_BF16(pf[mt][0], vf[dt][0], of[mt][dt]);
        of[mt][dt] = MFMA_BF16(pf[mt][1], vf[dt][1], of[mt][dt]);
      }

    __syncthreads();
  }

  // row-sum finalize: lane l15 holds full sum for row i = mt*16+l15 after
  // cross-quad reduce; broadcast to (quad,r) consumers.
  float rl[2][4];
#pragma unroll
  for (int mt = 0; mt < 2; ++mt) {
    float s = lsum[mt];
    s += __shfl_xor(s, 16);
    s += __shfl_xor(s, 32);
#pragma unroll
    for (int r = 0; r < 4; ++r)
      rl[mt][r] = __builtin_amdgcn_rcpf(__shfl(s, quad * 4 + r));
  }

  const int b = bh >> 4, h = bh & 15;
#pragma unroll
  for (int mt = 0; mt < 2; ++mt)
#pragma unroll
    for (int dt = 0; dt < 4; ++dt)
#pragma unroll
      for (int r = 0; r < 4; ++r) {
        const int ig = i0 + mt * 16 + quad * 4 + r;
        float v = of[mt][dt][r] * rl[mt][r];
        Ao[((size_t)(b * 1024 + ig)) * 1024 + h * 64 + dt * 16 + l15] = f32_to_bf16(v);
      }
}

// ---------------------------------------------------------------------------
extern "C" void kernel_launch(void* const* d_in, const int* in_sizes, int n_in,
                              void* d_out, int out_size, void* d_ws, size_t ws_size,
                              hipStream_t stream) {
  const float* x   = (const float*)d_in[0];
  const float* W_q = (const float*)d_in[1];
  const float* b_q = (const float*)d_in[2];
  const float* W_k = (const float*)d_in[3];
  const float* b_k = (const float*)d_in[4];
  const float* W_v = (const float*)d_in[5];
  const float* b_v = (const float*)d_in[6];
  const float* W_o = (const float*)d_in[7];
  const float* b_o = (const float*)d_in[8];
  const float* Er  = (const float*)d_in[9];
  float* out = (float*)d_out;

  char* ws = (char*)d_ws;
  unsigned short* xb   = (unsigned short*)(ws + (size_t)0);          // 8 MB
  unsigned short* Wcat = (unsigned short*)(ws + ((size_t)8  << 20)); // 6 MB (Wq|Wk|Wv)
  unsigned short* Wob  = (unsigned short*)(ws + ((size_t)14 << 20)); // 2 MB
  unsigned short* Qh   = (unsigned short*)(ws + ((size_t)16 << 20)); // 8 MB [bh][i][d]
  unsigned short* Kh   = (unsigned short*)(ws + ((size_t)24 << 20)); // 8 MB [bh][i][d]
  unsigned short* Vth  = (unsigned short*)(ws + ((size_t)32 << 20)); // 8 MB [bh][d][i]
  unsigned short* Aoh  = (unsigned short*)(ws + ((size_t)40 << 20)); // 8 MB [b*L][D]

  cast_all<<<8192, 256, 0, stream>>>(x, W_q, W_k, W_v, W_o, xb, Wcat, Wob);

  gemm_qkv<<<768, 256, 0, stream>>>(
      xb, Wcat, b_q, b_k, b_v, Er, Qh, Kh, Vth);

  attn_kernel<<<dim3(kB * kH, kL / 128), 256, 0, stream>>>(Qh, Kh, Vth, Aoh);

  gemm_out<<<dim3(16, 32), 256, 0, stream>>>(Aoh, Wob, b_o, out);
}